// Round 3
// baseline (451.640 us; speedup 1.0000x reference)
//
#include <hip/hip_runtime.h>
#include <math.h>

#define NBATCH 32
#define NCH 16
#define HW 65536
#define TPB 256
#define TILE_PX 512           // 16 ch x 512 px x 4 B = 32 KB LDS tile
#define TILES_PER_BLOCK 4
#define SLICES 32             // HW / (TILE_PX*TILES_PER_BLOCK)

// ws layout (floats)
#define WS_SUMS_S 0      // [b]: [0..15]=channel TOTALS, [16..31]=class-1 sums
#define WS_SUMS_T 1024
#define WS_N1     2048   // per-batch class-1 pixel count (32)
#define WS_LOSS   2080   // per-batch loss partials (32)
#define WS_FLOATS 2112

__device__ __forceinline__ float wave_sum(float v) {
#pragma unroll
  for (int off = 32; off > 0; off >>= 1) v += __shfl_down(v, off, 64);
  return v;
}

// grid (SLICES, NBATCH, 2). z=0 -> S, z=1 -> T.
__global__ __launch_bounds__(TPB) void k_sums(const float* __restrict__ S,
                                              const float* __restrict__ T,
                                              const int* __restrict__ tgt,
                                              float* __restrict__ ws) {
  __shared__ float buf[NCH * TILE_PX];   // [ch][px], 32 KB
  __shared__ float sinv[TILE_PX];        // per-px inv norm, 2 KB
  __shared__ float red[4][17];
  const int b = blockIdx.y, slice = blockIdx.x, which = blockIdx.z;
  const int tid = threadIdx.x;
  const int lane = tid & 63, wid = tid >> 6;
  const int m = wid >> 1;   // 0: totals, 1: class-1
  const int h = wid & 1;    // px half

  const float* __restrict__ Xb = (which ? T : S) + (size_t)b * NCH * HW;
  const int* __restrict__ tb = tgt + (size_t)b * HW;

  float acc[NCH];
#pragma unroll
  for (int c = 0; c < NCH; ++c) acc[c] = 0.f;
  float n1 = 0.f;

  const int tile0 = slice * TILES_PER_BLOCK;

  // prefetch tile 0: 8 independent float4 loads per thread
  float4 v[8];
  {
    const int base = tile0 * TILE_PX;
#pragma unroll
    for (int j = 0; j < 8; ++j) {
      const int ck = tid + j * TPB;           // chunk id in [0,2048)
      const int ch = ck >> 7, p4 = ck & 127;  // 128 float4-chunks per channel row
      v[j] = *(const float4*)(Xb + (size_t)ch * HW + base + p4 * 4);
    }
  }

  for (int t = 0; t < TILES_PER_BLOCK; ++t) {
    __syncthreads();  // previous tile's reads done
#pragma unroll
    for (int j = 0; j < 8; ++j) {
      const int ck = tid + j * TPB;
      const int ch = ck >> 7, p4 = ck & 127;
      *(float4*)(&buf[ch * TILE_PX + p4 * 4]) = v[j];
    }
    __syncthreads();

    // prefetch next tile (overlaps phases A/B below)
    if (t + 1 < TILES_PER_BLOCK) {
      const int base = (tile0 + t + 1) * TILE_PX;
#pragma unroll
      for (int j = 0; j < 8; ++j) {
        const int ck = tid + j * TPB;
        const int ch = ck >> 7, p4 = ck & 127;
        v[j] = *(const float4*)(Xb + (size_t)ch * HW + base + p4 * 4);
      }
    }

    // ---- phase A: inv norms for 2 px/thread ----
    {
      float ss0 = 0.f, ss1 = 0.f;
#pragma unroll
      for (int c = 0; c < NCH; ++c) {
        const float2 x = *(const float2*)(&buf[c * TILE_PX + tid * 2]);
        ss0 = fmaf(x.x, x.x, ss0);
        ss1 = fmaf(x.y, x.y, ss1);
      }
      float2 iv;
      iv.x = 1.f / fmaxf(sqrtf(ss0), 1e-12f);
      iv.y = 1.f / fmaxf(sqrtf(ss1), 1e-12f);
      *(float2*)(&sinv[tid * 2]) = iv;
    }
    __syncthreads();

    // ---- phase B: wave-specialized accumulate, 4 px/lane ----
    {
      const int px = h * 256 + lane * 4;
      float4 iv = *(const float4*)(&sinv[px]);
      if (m == 1) {
        const int4 tv = *(const int4*)(tb + (tile0 + t) * TILE_PX + px);
        const float m0 = (tv.x == 1) ? 1.f : 0.f;
        const float m1 = (tv.y == 1) ? 1.f : 0.f;
        const float m2 = (tv.z == 1) ? 1.f : 0.f;
        const float m3 = (tv.w == 1) ? 1.f : 0.f;
        if (which == 0) n1 += m0 + m1 + m2 + m3;
        iv.x *= m0; iv.y *= m1; iv.z *= m2; iv.w *= m3;  // exact: mask in {0,1}
      }
#pragma unroll
      for (int c = 0; c < NCH; ++c) {
        const float4 x = *(const float4*)(&buf[c * TILE_PX + px]);
        acc[c] = fmaf(x.x, iv.x, fmaf(x.y, iv.y, fmaf(x.z, iv.z, fmaf(x.w, iv.w, acc[c]))));
      }
    }
  }

#pragma unroll
  for (int c = 0; c < NCH; ++c) acc[c] = wave_sum(acc[c]);
  n1 = wave_sum(n1);
  if (lane == 0) {
#pragma unroll
    for (int c = 0; c < NCH; ++c) red[wid][c] = acc[c];
    red[wid][16] = n1;
  }
  __syncthreads();
  float* dst = ws + (which ? WS_SUMS_T : WS_SUMS_S) + b * 32;
  if (tid < 16) {
    atomicAdd(dst + tid, red[0][tid] + red[1][tid]);              // totals
  } else if (tid < 32) {
    const int c = tid - 16;
    atomicAdd(dst + 16 + c, red[2][c] + red[3][c]);               // class-1
  } else if (tid == 32 && which == 0) {
    atomicAdd(ws + WS_N1 + b, red[2][16] + red[3][16]);
  }
}

__device__ __forceinline__ float pc_one(float ss, float d0, float d1, int t,
                                        float nm0, float nm1) {
  const float n = sqrtf(ss);
  const float inv = 1.f / fmaxf(n, 1e-12f);
  const float na = n * inv;  // == |feat| after normalize
  const float c0 = (d0 * inv) / fmaxf(na * nm0, 1e-8f);
  const float c1 = (d1 * inv) / fmaxf(na * nm1, 1e-8f);
  return expf((t == 1) ? (c1 - c0) : (c0 - c1));
}

// grid (SLICES, NBATCH)
__global__ __launch_bounds__(TPB) void k_pass2(const float* __restrict__ S,
                                               const float* __restrict__ T,
                                               const int* __restrict__ tgt,
                                               float* __restrict__ ws) {
  __shared__ float buf[NCH * TILE_PX];  // 32 KB, shared by S then T half-phases
  __shared__ float sm[68];              // [0..63] means (S0,S1,T0,T1 x 16ch), [64..67] norms
  __shared__ float redl[4];
  const int b = blockIdx.y, slice = blockIdx.x;
  const int tid = threadIdx.x;

  if (tid < 64) {
    const int tt = tid >> 5, cls = (tid >> 4) & 1, ch = tid & 15;
    const float n1v = ws[WS_N1 + b];
    const float cnt = (cls ? n1v : ((float)HW - n1v)) + 1e-6f;
    const float* src = ws + (tt ? WS_SUMS_T : WS_SUMS_S) + b * 32;
    const float s = cls ? src[16 + ch] : (src[ch] - src[16 + ch]);  // cls0 = total - cls1
    sm[tid] = s / cnt;
  }
  __syncthreads();
  if (tid < 4) {  // tid = t*2+cls
    float ss = 0.f;
    const int base_ = (tid >> 1) * 32 + (tid & 1) * 16;
#pragma unroll
    for (int c = 0; c < NCH; ++c) { const float vv = sm[base_ + c]; ss = fmaf(vv, vv, ss); }
    sm[64 + tid] = sqrtf(ss);
  }
  __syncthreads();

  const int tile0 = slice * TILES_PER_BLOCK;
  const float* __restrict__ Sb = S + (size_t)b * NCH * HW;
  const float* __restrict__ Tb = T + (size_t)b * NCH * HW;
  const int* __restrict__ tb = tgt + (size_t)b * HW;

  float lacc = 0.f;
  float4 v[8];
  // prefetch S tile 0
  {
    const int base = tile0 * TILE_PX;
#pragma unroll
    for (int j = 0; j < 8; ++j) {
      const int ck = tid + j * TPB;
      const int ch = ck >> 7, p4 = ck & 127;
      v[j] = *(const float4*)(Sb + (size_t)ch * HW + base + p4 * 4);
    }
  }

  for (int t = 0; t < TILES_PER_BLOCK; ++t) {
    const int base = (tile0 + t) * TILE_PX;
    const int2 tv = *(const int2*)(tb + base + tid * 2);

    // ---- S half ----
    __syncthreads();
#pragma unroll
    for (int j = 0; j < 8; ++j) {
      const int ck = tid + j * TPB;
      const int ch = ck >> 7, p4 = ck & 127;
      *(float4*)(&buf[ch * TILE_PX + p4 * 4]) = v[j];
    }
    __syncthreads();
    // prefetch T tile t
#pragma unroll
    for (int j = 0; j < 8; ++j) {
      const int ck = tid + j * TPB;
      const int ch = ck >> 7, p4 = ck & 127;
      v[j] = *(const float4*)(Tb + (size_t)ch * HW + base + p4 * 4);
    }
    float pcS0, pcS1;
    {
      float ss0 = 0.f, ss1 = 0.f, d00 = 0.f, d01 = 0.f, d10 = 0.f, d11 = 0.f;
#pragma unroll
      for (int c = 0; c < NCH; ++c) {
        const float2 x = *(const float2*)(&buf[c * TILE_PX + tid * 2]);
        const float w0 = sm[c], w1 = sm[16 + c];
        ss0 = fmaf(x.x, x.x, ss0); ss1 = fmaf(x.y, x.y, ss1);
        d00 = fmaf(x.x, w0, d00);  d01 = fmaf(x.y, w0, d01);
        d10 = fmaf(x.x, w1, d10);  d11 = fmaf(x.y, w1, d11);
      }
      pcS0 = pc_one(ss0, d00, d10, tv.x, sm[64], sm[65]);
      pcS1 = pc_one(ss1, d01, d11, tv.y, sm[64], sm[65]);
    }

    // ---- T half ----
    __syncthreads();
#pragma unroll
    for (int j = 0; j < 8; ++j) {
      const int ck = tid + j * TPB;
      const int ch = ck >> 7, p4 = ck & 127;
      *(float4*)(&buf[ch * TILE_PX + p4 * 4]) = v[j];
    }
    __syncthreads();
    // prefetch S tile t+1
    if (t + 1 < TILES_PER_BLOCK) {
      const int nbase = (tile0 + t + 1) * TILE_PX;
#pragma unroll
      for (int j = 0; j < 8; ++j) {
        const int ck = tid + j * TPB;
        const int ch = ck >> 7, p4 = ck & 127;
        v[j] = *(const float4*)(Sb + (size_t)ch * HW + nbase + p4 * 4);
      }
    }
    {
      float ss0 = 0.f, ss1 = 0.f, d00 = 0.f, d01 = 0.f, d10 = 0.f, d11 = 0.f;
#pragma unroll
      for (int c = 0; c < NCH; ++c) {
        const float2 x = *(const float2*)(&buf[c * TILE_PX + tid * 2]);
        const float w0 = sm[32 + c], w1 = sm[48 + c];
        ss0 = fmaf(x.x, x.x, ss0); ss1 = fmaf(x.y, x.y, ss1);
        d00 = fmaf(x.x, w0, d00);  d01 = fmaf(x.y, w0, d01);
        d10 = fmaf(x.x, w1, d10);  d11 = fmaf(x.y, w1, d11);
      }
      const float pcT0 = pc_one(ss0, d00, d10, tv.x, sm[66], sm[67]);
      const float pcT1 = pc_one(ss1, d01, d11, tv.y, sm[66], sm[67]);
      const float e0 = pcS0 - pcT0, e1 = pcS1 - pcT1;
      lacc += e0 * e0 + e1 * e1;
    }
  }

  lacc = wave_sum(lacc);
  if ((tid & 63) == 0) redl[tid >> 6] = lacc;
  __syncthreads();
  if (tid == 0)
    atomicAdd(ws + WS_LOSS + b, redl[0] + redl[1] + redl[2] + redl[3]);
}

__global__ void k_final(const float* __restrict__ ws, float* __restrict__ out) {
  float s = 0.f;
  for (int b = 0; b < NBATCH; ++b) s += ws[WS_LOSS + b];
  out[0] = s * (1.f / 2097152.f);  // N = 32*256*256 = 2^21, exact
}

extern "C" void kernel_launch(void* const* d_in, const int* in_sizes, int n_in,
                              void* d_out, int out_size, void* d_ws, size_t ws_size,
                              hipStream_t stream) {
  const float* S = (const float*)d_in[0];
  const float* T = (const float*)d_in[1];
  const int* tgt = (const int*)d_in[2];
  float* ws = (float*)d_ws;
  float* out = (float*)d_out;

  hipMemsetAsync(d_ws, 0, WS_FLOATS * sizeof(float), stream);
  dim3 g1(SLICES, NBATCH, 2);
  k_sums<<<g1, TPB, 0, stream>>>(S, T, tgt, ws);
  dim3 g2(SLICES, NBATCH);
  k_pass2<<<g2, TPB, 0, stream>>>(S, T, tgt, ws);
  k_final<<<1, 1, 0, stream>>>(ws, out);
}

// Round 4
// 342.588 us; speedup vs baseline: 1.3183x; 1.3183x over previous
//
#include <hip/hip_runtime.h>
#include <math.h>

#define NBATCH 32
#define NCH 16
#define HW 65536
#define TPB 256
#define TILE_PX 256   // one channel row per tile = 1 KB = one dwordx4 DMA per wave
#define TILES 8       // tiles per block
#define SLICES 32     // HW / (TILE_PX*TILES)

// ws float layout
#define WS_SUMS_S 0      // [b*32+i]: i<16 channel totals, i>=16 class-1 sums
#define WS_SUMS_T 1024
#define WS_N1     2048   // per-batch class-1 pixel count
#define WS_LOSS   2080   // per-batch loss partials
#define WS_MEANS  2112   // [b*68+i]: 0..15 S0,16..31 S1,32..47 T0,48..63 T1,64..67 norms
#define WS_FLOATS 4288

__device__ __forceinline__ float wave_sum(float v) {
#pragma unroll
  for (int off = 32; off > 0; off >>= 1) v += __shfl_down(v, off, 64);
  return v;
}

// async global->LDS, 16 B per lane; LDS dest is wave-uniform base + lane*16
__device__ __forceinline__ void ld16(const float* g, float* l) {
  __builtin_amdgcn_global_load_lds(
      (const __attribute__((address_space(1))) unsigned int*)g,
      (__attribute__((address_space(3))) unsigned int*)l, 16, 0, 0);
}

// grid (SLICES, NBATCH, 2). z=0 -> S, z=1 -> T.
__global__ __launch_bounds__(TPB) void k_sums(const float* __restrict__ S,
                                              const float* __restrict__ T,
                                              const int* __restrict__ tgt,
                                              float* __restrict__ ws) {
  __shared__ float buf[2][NCH * TILE_PX];  // 2 x 16 KB
  __shared__ float sinv[TILE_PX];
  const int b = blockIdx.y, slice = blockIdx.x, which = blockIdx.z;
  const int tid = threadIdx.x, lane = tid & 63, wid = tid >> 6;

  const float* __restrict__ Xb = (which ? T : S) + (size_t)b * NCH * HW;
  const int* __restrict__ tb = tgt + (size_t)b * HW;

  float tot[4], c1[4];
#pragma unroll
  for (int c = 0; c < 4; ++c) { tot[c] = 0.f; c1[c] = 0.f; }
  float n1 = 0.f;
  const int base0 = slice * TILES * TILE_PX;

  // stage tile 0: wave wid stages channels 4*wid..4*wid+3 (1 KB row = 1 DMA each)
#pragma unroll
  for (int c = 0; c < 4; ++c) {
    const int ch = wid * 4 + c;
    ld16(Xb + (size_t)ch * HW + base0 + lane * 4, &buf[0][ch * TILE_PX]);
  }

  for (int t = 0; t < TILES; ++t) {
    const float* cur = buf[t & 1];
    __syncthreads();  // DMA tile t drained (issued one compute-phase ago); other buf free

    // phase A: per-px inv norm (1 px/thread, bank-conflict-free b32 reads)
    float ss = 0.f;
#pragma unroll
    for (int c = 0; c < NCH; ++c) {
      const float x = cur[c * TILE_PX + tid];
      ss = fmaf(x, x, ss);
    }
    sinv[tid] = 1.f / fmaxf(sqrtf(ss), 1e-12f);
    __syncthreads();  // sinv visible; no DMA outstanding here (cheap drain)

    // prefetch tile t+1 (latency hidden by phase B + next top-barrier overlap)
    if (t + 1 < TILES) {
      const int nbase = base0 + (t + 1) * TILE_PX;
#pragma unroll
      for (int c = 0; c < 4; ++c) {
        const int ch = wid * 4 + c;
        ld16(Xb + (size_t)ch * HW + nbase + lane * 4, &buf[(t + 1) & 1][ch * TILE_PX]);
      }
    }

    // phase B: wave = its 4 channels, lane = 4 px; 8 persistent accumulators
    const int px = lane * 4;
    const float4 iv = *(const float4*)(&sinv[px]);
    const int4 tv = *(const int4*)(tb + base0 + t * TILE_PX + px);
    const float m0 = (tv.x == 1) ? 1.f : 0.f;
    const float m1 = (tv.y == 1) ? 1.f : 0.f;
    const float m2 = (tv.z == 1) ? 1.f : 0.f;
    const float m3 = (tv.w == 1) ? 1.f : 0.f;
    if (wid == 0 && which == 0) n1 += m0 + m1 + m2 + m3;
    const float4 miv = {iv.x * m0, iv.y * m1, iv.z * m2, iv.w * m3};  // exact: mask in {0,1}
#pragma unroll
    for (int c = 0; c < 4; ++c) {
      const int ch = wid * 4 + c;
      const float4 x = *(const float4*)(&cur[ch * TILE_PX + px]);
      tot[c] = fmaf(x.x, iv.x, fmaf(x.y, iv.y, fmaf(x.z, iv.z, fmaf(x.w, iv.w, tot[c]))));
      c1[c] = fmaf(x.x, miv.x, fmaf(x.y, miv.y, fmaf(x.z, miv.z, fmaf(x.w, miv.w, c1[c]))));
    }
  }

#pragma unroll
  for (int c = 0; c < 4; ++c) { tot[c] = wave_sum(tot[c]); c1[c] = wave_sum(c1[c]); }
  n1 = wave_sum(n1);
  if (lane == 0) {
    float* dst = ws + (which ? WS_SUMS_T : WS_SUMS_S) + b * 32;
#pragma unroll
    for (int c = 0; c < 4; ++c) {
      atomicAdd(dst + wid * 4 + c, tot[c]);        // channel totals
      atomicAdd(dst + 16 + wid * 4 + c, c1[c]);    // class-1 sums
    }
    if (wid == 0 && which == 0) atomicAdd(ws + WS_N1 + b, n1);
  }
}

// grid (NBATCH), 64 threads: per-batch means (+cls0 = total - cls1) and mean norms
__global__ void k_prep(float* __restrict__ ws) {
  __shared__ float sm[64];
  const int b = blockIdx.x, tid = threadIdx.x;
  const int tt = tid >> 5, cls = (tid >> 4) & 1, ch = tid & 15;
  const float n1v = ws[WS_N1 + b];
  const float cnt = (cls ? n1v : ((float)HW - n1v)) + 1e-6f;
  const float* src = ws + (tt ? WS_SUMS_T : WS_SUMS_S) + b * 32;
  const float s = cls ? src[16 + ch] : (src[ch] - src[16 + ch]);
  const float m = s / cnt;
  sm[tid] = m;
  ws[WS_MEANS + b * 68 + tid] = m;
  __syncthreads();
  if (tid < 4) {  // tid = tt*2+cls over groups S0,S1,T0,T1
    float ssn = 0.f;
#pragma unroll
    for (int c = 0; c < NCH; ++c) {
      const float v = sm[tid * 16 + c];
      ssn = fmaf(v, v, ssn);
    }
    ws[WS_MEANS + b * 68 + 64 + tid] = sqrtf(ssn);
  }
}

__device__ __forceinline__ float pc_one(float ss, float d0, float d1, int t,
                                        float nm0, float nm1) {
  const float n = sqrtf(ss);
  const float inv = 1.f / fmaxf(n, 1e-12f);
  const float na = n * inv;  // == |feat| after normalize
  const float c0 = (d0 * inv) / fmaxf(na * nm0, 1e-8f);
  const float c1 = (d1 * inv) / fmaxf(na * nm1, 1e-8f);
  return expf((t == 1) ? (c1 - c0) : (c0 - c1));
}

// grid (SLICES, NBATCH). S/T half-tiles ping-pong through two LDS buffers.
__global__ __launch_bounds__(TPB) void k_pass2(const float* __restrict__ S,
                                               const float* __restrict__ T,
                                               const int* __restrict__ tgt,
                                               float* __restrict__ ws) {
  __shared__ float bufS[NCH * TILE_PX];
  __shared__ float bufT[NCH * TILE_PX];
  __shared__ float redl[4];
  const int b = blockIdx.y, slice = blockIdx.x;
  const int tid = threadIdx.x, lane = tid & 63, wid = tid >> 6;

  const float* __restrict__ Sb = S + (size_t)b * NCH * HW;
  const float* __restrict__ Tb = T + (size_t)b * NCH * HW;
  const int* __restrict__ tb = tgt + (size_t)b * HW;
  const float* __restrict__ wm = ws + WS_MEANS + b * 68;  // wave-uniform -> SGPRs

  const float nmS0 = wm[64], nmS1 = wm[65], nmT0 = wm[66], nmT1 = wm[67];
  const int base0 = slice * TILES * TILE_PX;
  float lacc = 0.f;

  // stage S tile 0
#pragma unroll
  for (int c = 0; c < 4; ++c) {
    const int ch = wid * 4 + c;
    ld16(Sb + (size_t)ch * HW + base0 + lane * 4, &bufS[ch * TILE_PX]);
  }

  for (int t = 0; t < TILES; ++t) {
    const int base = base0 + t * TILE_PX;
    __syncthreads();  // S tile t drained; bufT reads of t-1 done
    // stage T tile t (hidden by S-compute)
#pragma unroll
    for (int c = 0; c < 4; ++c) {
      const int ch = wid * 4 + c;
      ld16(Tb + (size_t)ch * HW + base + lane * 4, &bufT[ch * TILE_PX]);
    }
    const int tv = tb[base + tid];

    float ss = 0.f, d0 = 0.f, d1 = 0.f;
#pragma unroll
    for (int c = 0; c < NCH; ++c) {
      const float x = bufS[c * TILE_PX + tid];
      ss = fmaf(x, x, ss);
      d0 = fmaf(x, wm[c], d0);
      d1 = fmaf(x, wm[16 + c], d1);
    }
    const float pcS = pc_one(ss, d0, d1, tv, nmS0, nmS1);

    __syncthreads();  // T tile t drained; bufS reads done
    // stage S tile t+1 (hidden by T-compute)
    if (t + 1 < TILES) {
      const int nbase = base0 + (t + 1) * TILE_PX;
#pragma unroll
      for (int c = 0; c < 4; ++c) {
        const int ch = wid * 4 + c;
        ld16(Sb + (size_t)ch * HW + nbase + lane * 4, &bufS[ch * TILE_PX]);
      }
    }

    ss = 0.f; d0 = 0.f; d1 = 0.f;
#pragma unroll
    for (int c = 0; c < NCH; ++c) {
      const float x = bufT[c * TILE_PX + tid];
      ss = fmaf(x, x, ss);
      d0 = fmaf(x, wm[32 + c], d0);
      d1 = fmaf(x, wm[48 + c], d1);
    }
    const float pcT = pc_one(ss, d0, d1, tv, nmT0, nmT1);
    const float e = pcS - pcT;
    lacc = fmaf(e, e, lacc);
  }

  lacc = wave_sum(lacc);
  if (lane == 0) redl[wid] = lacc;
  __syncthreads();
  if (tid == 0) atomicAdd(ws + WS_LOSS + b, redl[0] + redl[1] + redl[2] + redl[3]);
}

__global__ void k_final(const float* __restrict__ ws, float* __restrict__ out) {
  float s = 0.f;
  for (int b = 0; b < NBATCH; ++b) s += ws[WS_LOSS + b];
  out[0] = s * (1.f / 2097152.f);  // N = 32*256*256 = 2^21, exact
}

extern "C" void kernel_launch(void* const* d_in, const int* in_sizes, int n_in,
                              void* d_out, int out_size, void* d_ws, size_t ws_size,
                              hipStream_t stream) {
  const float* S = (const float*)d_in[0];
  const float* T = (const float*)d_in[1];
  const int* tgt = (const int*)d_in[2];
  float* ws = (float*)d_ws;
  float* out = (float*)d_out;

  hipMemsetAsync(d_ws, 0, WS_FLOATS * sizeof(float), stream);
  dim3 g1(SLICES, NBATCH, 2);
  k_sums<<<g1, TPB, 0, stream>>>(S, T, tgt, ws);
  k_prep<<<NBATCH, 64, 0, stream>>>(ws);
  dim3 g2(SLICES, NBATCH);
  k_pass2<<<g2, TPB, 0, stream>>>(S, T, tgt, ws);
  k_final<<<1, 1, 0, stream>>>(ws, out);
}